// Round 6
// baseline (264.627 us; speedup 1.0000x reference)
//
#include <hip/hip_runtime.h>

// NNGLS: y_decor, o_decor, o for N=200000, M=20, MLP 64->256->1.
//
// K1 (mlp_mfma_kernel): split-bf16 MFMA GEMM (x=xh+xl, w1=wh+wl; 3 passes).
//     NOW PERSISTENT: 512 blocks (2/CU, LDS-capped) grid-stride over the 782
//     node-tiles; w1 staged to LDS ONCE per block (was: re-staged by every
//     block, incl. the 270 second-round blocks), tail smoothed.
// K2 (solve_kernel): QUAD-SPLIT elimination, round-0-proven code shape
//     (one function body, rolled `#pragma unroll 1` loops, switch(k) literal
//     copies, literal-pattern ds_swizzle) + ROUND-1 PHASE-SPLIT: 5 rolled
//     4-step loops; phase P only touches rows >= 4P, slots j >= P, gathers
//     R >= 4P. All omitted ops were exact fma(-0,*,a) no-ops or unused
//     gathers => bit-identical results. Per-lane array ops 2040 -> 1080,
//     quad gathers 420 -> 240; AGPR read/write inflation shrinks with them.
//     Layout (r5): lane h=tid&3 owns cols c===h (mod4); slot j stores col
//     4j+h rows 0..4j+3; col 20 replicated -> 81 floats/lane; bv: lanes 0,2
//     carry y, lanes 1,3 carry o.

#define MM   20
#define PP   64
#define HH   256
#define EPSF 1e-12f

// quad-split storage: slot j (col 4j+h), rows 0..4j+3 at offset 2j(j+1);
// replicated col 20 at offset 60.
#define CSE(j, r) csx[2*(j)*((j)+1) + (r)]
#define C20(r)    csx[60 + (r)]

typedef __attribute__((ext_vector_type(8))) short bf16x8;
typedef __attribute__((ext_vector_type(4))) float f32x4;

static __device__ __forceinline__ unsigned short f2bf(float f) {
    unsigned int u = __builtin_bit_cast(unsigned int, f);
    u += 0x7fffu + ((u >> 16) & 1u);          // RNE
    return (unsigned short)(u >> 16);
}
static __device__ __forceinline__ float bf2f(unsigned short h) {
    unsigned int u = ((unsigned int)h) << 16;
    return __builtin_bit_cast(float, u);
}

__global__ __launch_bounds__(256, 2)
void mlp_mfma_kernel(const float* __restrict__ x,
                     const float* __restrict__ w1,
                     const float* __restrict__ b1,
                     const float* __restrict__ w2,
                     const float* __restrict__ b2,
                     float* __restrict__ o_out, int n, int ntiles)
{
    __shared__ __align__(16) short swh[PP * HH];   // 32 KB  w1 hi, frag order
    __shared__ __align__(16) short swl[PP * HH];   // 32 KB  w1 lo
    const int tid = threadIdx.x;

    // ---- stage w1 -> frag-ordered bf16 hi/lo (ONCE per persistent block) ----
    {
        const int col = tid;                       // 256 cols, one per thread
        const int t = col >> 4, nn = col & 15;
        #pragma unroll
        for (int g = 0; g < 8; ++g) {              // k = g*8 + u
            const int s = g >> 2, q = g & 3;
            bf16x8 hv, lv;
            #pragma unroll
            for (int u = 0; u < 8; ++u) {
                float v = w1[(g * 8 + u) * HH + col];
                unsigned short h = f2bf(v);
                hv[u] = (short)h;
                lv[u] = (short)f2bf(v - bf2f(h));
            }
            const int base = ((((t * 2 + s) * 4 + q) * 16) + nn) * 8;
            *(bf16x8*)&swh[base] = hv;
            *(bf16x8*)&swl[base] = lv;
        }
    }
    __syncthreads();

    const int lane = tid & 63;
    const int wv   = tid >> 6;
    const int nn   = lane & 15;      // A-row (node) / B-col (hidden) / C-col
    const int q    = lane >> 4;      // quad

    float w2v[16], b1v[16];
    #pragma unroll
    for (int t = 0; t < 16; ++t) {
        w2v[t] = w2[t * 16 + nn];
        b1v[t] = b1[t * 16 + nn];
    }
    const float bb = b2[0];

    for (int tile = blockIdx.x; tile < ntiles; tile += gridDim.x) {
        const int wb = tile * 256 + wv * 64;       // first node of this wave

        // ---- A fragments: 4 M-tiles x 2 k-steps, split hi/lo ----
        bf16x8 ah[4][2], al[4][2];
        #pragma unroll
        for (int mt = 0; mt < 4; ++mt) {
            const int row = wb + mt * 16 + nn;
            #pragma unroll
            for (int s = 0; s < 2; ++s) {
                float v[8];
                if (row < n) {
                    const float* xp = x + (size_t)row * PP + s * 32 + q * 8;
                    float4 va = *(const float4*)(xp);
                    float4 vb = *(const float4*)(xp + 4);
                    v[0]=va.x; v[1]=va.y; v[2]=va.z; v[3]=va.w;
                    v[4]=vb.x; v[5]=vb.y; v[6]=vb.z; v[7]=vb.w;
                } else {
                    #pragma unroll
                    for (int u = 0; u < 8; ++u) v[u] = 0.0f;
                }
                bf16x8 h, l;
                #pragma unroll
                for (int u = 0; u < 8; ++u) {
                    unsigned short hb = f2bf(v[u]);
                    h[u] = (short)hb;
                    l[u] = (short)f2bf(v[u] - bf2f(hb));
                }
                ah[mt][s] = h;
                al[mt][s] = l;
            }
        }

        float part[4][4];
        #pragma unroll
        for (int mt = 0; mt < 4; ++mt)
            #pragma unroll
            for (int r = 0; r < 4; ++r) part[mt][r] = 0.0f;

        #pragma unroll
        for (int t = 0; t < 16; ++t) {
            f32x4 acc[4];
            #pragma unroll
            for (int mt = 0; mt < 4; ++mt) acc[mt] = (f32x4)(0.0f);
            #pragma unroll
            for (int s = 0; s < 2; ++s) {
                const int fb = ((((t * 2 + s) * 4 + q) * 16) + nn) * 8;
                bf16x8 bh = *(const bf16x8*)&swh[fb];
                bf16x8 bl = *(const bf16x8*)&swl[fb];
                #pragma unroll
                for (int mt = 0; mt < 4; ++mt) {
                    acc[mt] = __builtin_amdgcn_mfma_f32_16x16x32_bf16(ah[mt][s], bh, acc[mt], 0, 0, 0);
                    acc[mt] = __builtin_amdgcn_mfma_f32_16x16x32_bf16(al[mt][s], bh, acc[mt], 0, 0, 0);
                    acc[mt] = __builtin_amdgcn_mfma_f32_16x16x32_bf16(ah[mt][s], bl, acc[mt], 0, 0, 0);
                }
            }
            #pragma unroll
            for (int mt = 0; mt < 4; ++mt)
                #pragma unroll
                for (int r = 0; r < 4; ++r)
                    part[mt][r] = fmaf(fmaxf(acc[mt][r] + b1v[t], 0.0f), w2v[t], part[mt][r]);
        }

        #pragma unroll
        for (int w = 1; w < 16; w <<= 1)
            #pragma unroll
            for (int mt = 0; mt < 4; ++mt)
                #pragma unroll
                for (int r = 0; r < 4; ++r)
                    part[mt][r] += __shfl_xor(part[mt][r], w, 64);

        if (nn == 0) {
            #pragma unroll
            for (int mt = 0; mt < 4; ++mt) {
                const int row = wb + mt * 16 + q * 4;   // rows q*4+reg
                if (row < n) {
                    float4 o4 = make_float4(part[mt][0] + bb, part[mt][1] + bb,
                                            part[mt][2] + bb, part[mt][3] + bb);
                    *(float4*)&o_out[row] = o4;
                }
            }
        }
    }
}

// quad broadcast of sub-lane (s) within each 4-lane group, literal pattern
#define QSWZ(v, s) __builtin_bit_cast(float, __builtin_amdgcn_ds_swizzle( \
    __builtin_bit_cast(int, (v)), 0x8000 | (0x55 * (s))))

#define GATH(R) mall[R] = QSWZ(mv[(R) >> 2], (R) & 3);

// case K of phase P: copy pivot-row data (literal indices), broadcast pivot
#define SCASE(K, P) case K: {                                              \
    _Pragma("unroll")                                                      \
    for (int j = (P); j < 5; ++j) pk[j] = CSE(j, (K));                     \
    p20 = C20(K); pbv = bv[K];                                             \
    pd  = QSWZ(pk[(P)], (K) & 3);                                          \
} break;

__global__ __launch_bounds__(256, 2)
void solve_kernel(const float* __restrict__ pos,
                  const float* __restrict__ y,
                  const int*   __restrict__ nbr,
                  const float* __restrict__ theta,
                  const float* __restrict__ o_in,
                  float* __restrict__ yd,
                  float* __restrict__ od, int n)
{
    const int tid  = threadIdx.x;
    const int h_   = tid & 3;                         // column class
    const int i    = blockIdx.x * 64 + (tid >> 2);    // node (4 lanes/node)
    if (i >= n) return;

    const float sigma_sq = theta[0];
    const float phi      = theta[1];
    const float tau      = theta[2];
    const float tau_sq   = tau * sigma_sq;

    const float L2E = 1.44269504088896340736f;
    const float c1  = -phi * L2E;                       // exp(-phi*d) = exp2(c1*d)
    const float c0  = __builtin_amdgcn_logf(sigma_sq);  // log2(sigma^2)

    const float sqrtEPS = __builtin_amdgcn_sqrtf(EPSF);
    const float diagA   = __builtin_amdgcn_exp2f(fmaf(sqrtEPS, c1, c0)) + tau_sq;
    const float diagB   = sigma_sq + tau;               // border diagonal

    // ---- neighbor indices (static indices only) ----
    int idx[MM];
    const int4* nb4 = (const int4*)(nbr + (size_t)i * MM);
    #pragma unroll
    for (int k = 0; k < MM / 4; ++k) {
        int4 v = nb4[k];
        idx[4*k] = v.x; idx[4*k+1] = v.y; idx[4*k+2] = v.z; idx[4*k+3] = v.w;
    }

    // row coords (all 21, static-indexed)
    float px[21], py[21];
    const float2* pos2 = (const float2*)pos;
    #pragma unroll
    for (int j = 0; j < MM; ++j) {
        float2 p = pos2[idx[j]];
        px[j] = p.x; py[j] = p.y;
    }
    {
        float2 p = pos2[i];
        px[20] = p.x; py[20] = p.y;
    }

    // my columns' coords: re-gathered from nbr/pos (runtime ADDRESS is fine;
    // runtime index into a register array is not).
    float cx[5], cy[5];
    #pragma unroll
    for (int j = 0; j < 5; ++j) {
        int cj = nbr[(size_t)i * MM + 4*j + h_];
        float2 p = pos2[cj];
        cx[j] = p.x; cy[j] = p.y;
    }

    // border vector: lanes 0,2 carry y; lanes 1,3 carry o
    float bv[21];
    {
        const float* src = (h_ & 1) ? o_in : y;
        #pragma unroll
        for (int j = 0; j < MM; ++j) bv[j] = src[idx[j]];
        bv[20] = src[i];
    }

    // ---- build my slots (rows 0..4j+3 of col 4j+h) + replicated col 20 ----
    float csx[81];
    #pragma unroll
    for (int j = 0; j < 5; ++j) {
        #pragma unroll
        for (int r = 0; r <= 4*j + 3; ++r) {
            float dx = px[r] - cx[j];
            float dy = py[r] - cy[j];
            float d  = __builtin_amdgcn_sqrtf(fmaf(dx, dx, fmaf(dy, dy, EPSF)));
            float v  = __builtin_amdgcn_exp2f(fmaf(d, c1, c0));
            v = (r == 4*j + h_) ? diagA : v;       // diagonal of col 4j+h
            CSE(j, r) = v;
        }
    }
    #pragma unroll
    for (int r = 0; r < 20; ++r) {
        float dx = px[r] - px[20];
        float dy = py[r] - py[20];
        float d  = __builtin_amdgcn_sqrtf(fmaf(dx, dx, fmaf(dy, dy, EPSF)));
        C20(r)   = __builtin_amdgcn_exp2f(fmaf(d, c1, c0));
    }
    C20(20) = diagB;

    // ---- elimination: 5 phases x 4 rolled steps (round-0 shape per phase,
    //      round-1 range shrinking per phase). Omitted ops were exact no-ops.
    float pk[5], mv[5], mall[21], p20, pbv, pd;

    // ===== phase 0: k = 0..3, rows/slots/gathers from 0 =====
    #pragma unroll 1
    for (int k = 0; k < 4; ++k) {
        switch (k) {
        SCASE(0,0) SCASE(1,0) SCASE(2,0) SCASE(3,0)
        default: break;
        }
        float rp = __builtin_amdgcn_rcpf(pd);
        rp = rp * (2.0f - pd * rp);
        #pragma unroll
        for (int j = 0; j < 5; ++j)
            mv[j] = (4*j + h_ > k) ? pk[j] * rp : 0.0f;
        GATH(0)  GATH(1)  GATH(2)  GATH(3)  GATH(4)  GATH(5)  GATH(6)
        GATH(7)  GATH(8)  GATH(9)  GATH(10) GATH(11) GATH(12) GATH(13)
        GATH(14) GATH(15) GATH(16) GATH(17) GATH(18) GATH(19)
        mall[20] = p20 * rp;
        #pragma unroll
        for (int j = 0; j < 5; ++j) {
            float pkj = pk[j];
            #pragma unroll
            for (int r = 0; r <= 4*j + 3; ++r)
                CSE(j, r) = fmaf(-mall[r], pkj, CSE(j, r));
        }
        #pragma unroll
        for (int r = 0; r <= 20; ++r) {
            C20(r) = fmaf(-mall[r], p20, C20(r));
            bv[r]  = fmaf(-mall[r], pbv, bv[r]);
        }
    }

    // ===== phase 1: k = 4..7, rows >= 4, slots j >= 1 =====
    #pragma unroll 1
    for (int k = 4; k < 8; ++k) {
        switch (k) {
        SCASE(4,1) SCASE(5,1) SCASE(6,1) SCASE(7,1)
        default: break;
        }
        float rp = __builtin_amdgcn_rcpf(pd);
        rp = rp * (2.0f - pd * rp);
        #pragma unroll
        for (int j = 1; j < 5; ++j)
            mv[j] = (4*j + h_ > k) ? pk[j] * rp : 0.0f;
        GATH(4)  GATH(5)  GATH(6)  GATH(7)  GATH(8)  GATH(9)  GATH(10)
        GATH(11) GATH(12) GATH(13) GATH(14) GATH(15) GATH(16) GATH(17)
        GATH(18) GATH(19)
        mall[20] = p20 * rp;
        #pragma unroll
        for (int j = 1; j < 5; ++j) {
            float pkj = pk[j];
            #pragma unroll
            for (int r = 4; r <= 4*j + 3; ++r)
                CSE(j, r) = fmaf(-mall[r], pkj, CSE(j, r));
        }
        #pragma unroll
        for (int r = 4; r <= 20; ++r) {
            C20(r) = fmaf(-mall[r], p20, C20(r));
            bv[r]  = fmaf(-mall[r], pbv, bv[r]);
        }
    }

    // ===== phase 2: k = 8..11, rows >= 8, slots j >= 2 =====
    #pragma unroll 1
    for (int k = 8; k < 12; ++k) {
        switch (k) {
        SCASE(8,2) SCASE(9,2) SCASE(10,2) SCASE(11,2)
        default: break;
        }
        float rp = __builtin_amdgcn_rcpf(pd);
        rp = rp * (2.0f - pd * rp);
        #pragma unroll
        for (int j = 2; j < 5; ++j)
            mv[j] = (4*j + h_ > k) ? pk[j] * rp : 0.0f;
        GATH(8)  GATH(9)  GATH(10) GATH(11) GATH(12) GATH(13) GATH(14)
        GATH(15) GATH(16) GATH(17) GATH(18) GATH(19)
        mall[20] = p20 * rp;
        #pragma unroll
        for (int j = 2; j < 5; ++j) {
            float pkj = pk[j];
            #pragma unroll
            for (int r = 8; r <= 4*j + 3; ++r)
                CSE(j, r) = fmaf(-mall[r], pkj, CSE(j, r));
        }
        #pragma unroll
        for (int r = 8; r <= 20; ++r) {
            C20(r) = fmaf(-mall[r], p20, C20(r));
            bv[r]  = fmaf(-mall[r], pbv, bv[r]);
        }
    }

    // ===== phase 3: k = 12..15, rows >= 12, slots j >= 3 =====
    #pragma unroll 1
    for (int k = 12; k < 16; ++k) {
        switch (k) {
        SCASE(12,3) SCASE(13,3) SCASE(14,3) SCASE(15,3)
        default: break;
        }
        float rp = __builtin_amdgcn_rcpf(pd);
        rp = rp * (2.0f - pd * rp);
        #pragma unroll
        for (int j = 3; j < 5; ++j)
            mv[j] = (4*j + h_ > k) ? pk[j] * rp : 0.0f;
        GATH(12) GATH(13) GATH(14) GATH(15) GATH(16) GATH(17) GATH(18)
        GATH(19)
        mall[20] = p20 * rp;
        #pragma unroll
        for (int j = 3; j < 5; ++j) {
            float pkj = pk[j];
            #pragma unroll
            for (int r = 12; r <= 4*j + 3; ++r)
                CSE(j, r) = fmaf(-mall[r], pkj, CSE(j, r));
        }
        #pragma unroll
        for (int r = 12; r <= 20; ++r) {
            C20(r) = fmaf(-mall[r], p20, C20(r));
            bv[r]  = fmaf(-mall[r], pbv, bv[r]);
        }
    }

    // ===== phase 4: k = 16..19, rows >= 16, slot j = 4 =====
    #pragma unroll 1
    for (int k = 16; k < 20; ++k) {
        switch (k) {
        SCASE(16,4) SCASE(17,4) SCASE(18,4) SCASE(19,4)
        default: break;
        }
        float rp = __builtin_amdgcn_rcpf(pd);
        rp = rp * (2.0f - pd * rp);
        mv[4] = (16 + h_ > k) ? pk[4] * rp : 0.0f;
        GATH(16) GATH(17) GATH(18) GATH(19)
        mall[20] = p20 * rp;
        {
            float pkj = pk[4];
            #pragma unroll
            for (int r = 16; r <= 19; ++r)
                CSE(4, r) = fmaf(-mall[r], pkj, CSE(4, r));
        }
        #pragma unroll
        for (int r = 16; r <= 20; ++r) {
            C20(r) = fmaf(-mall[r], p20, C20(r));
            bv[r]  = fmaf(-mall[r], pbv, bv[r]);
        }
    }

    // f = a[20][20], replicated on every lane
    float f  = C20(20);
    float is = __builtin_amdgcn_rsqf(f);
    is = is * fmaf(-0.5f * f * is, is, 1.5f);

    if (h_ == 0)      yd[i] = bv[20] * is;   // lanes 0/2 carry y
    else if (h_ == 1) od[i] = bv[20] * is;   // lanes 1/3 carry o
}

extern "C" void kernel_launch(void* const* d_in, const int* in_sizes, int n_in,
                              void* d_out, int out_size, void* d_ws, size_t ws_size,
                              hipStream_t stream)
{
    const float* x     = (const float*)d_in[0];
    const float* pos   = (const float*)d_in[1];
    const float* y     = (const float*)d_in[2];
    const int*   nbr   = (const int*)  d_in[3];
    const float* theta = (const float*)d_in[4];
    const float* w1    = (const float*)d_in[5];
    const float* b1    = (const float*)d_in[6];
    const float* w2    = (const float*)d_in[7];
    const float* b2    = (const float*)d_in[8];

    const int n = in_sizes[2];                 // N
    float* out = (float*)d_out;
    float* yd = out;
    float* od = out + (size_t)n;
    float* oo = out + 2 * (size_t)n;

    const int ntiles = (n + 255) / 256;
    const int grid1  = ntiles < 512 ? ntiles : 512;   // 2 blocks/CU, persistent
    mlp_mfma_kernel<<<grid1, 256, 0, stream>>>(x, w1, b1, w2, b2, oo, n, ntiles);
    // 64 nodes per 256-thread block (4 lanes per node)
    solve_kernel<<<(n + 63) / 64, 256, 0, stream>>>(pos, y, nbr, theta, oo, yd, od, n);
}

// Round 7
// 195.759 us; speedup vs baseline: 1.3518x; 1.3518x over previous
//
#include <hip/hip_runtime.h>

// NNGLS: y_decor, o_decor, o for N=200000, M=20, MLP 64->256->1.
//
// K1 (mlp_mfma_kernel): split-bf16 MFMA GEMM (x=xh+xl, w1=wh+wl; 3 passes
//     ah*bh + al*bh + ah*bl => ~fp32 accuracy). ROUND-7 DE-SPILL:
//     r6 counters showed FETCH 140MB / WRITE 150MB (~240MB scratch): the
//     4-M-tile wave carried ah/al=64 VGPR + w2v/b1v=32 + acc16 + part16 >
//     128 => A-frags spilled in the hot loop (VALUBusy 8.5%). Now:
//       * 2 M-tiles per wave (32 nodes/wave, 128/block, grid 1563):
//         ah/al 32, acc 8, part 8.
//       * b1/w2 staged to LDS (2KB), read per-t (addr depends only on nn
//         => 4-lane broadcast, conflict-free): frees 32 VGPRs.
//       * non-persistent again (persistence was neutral; w1 re-staging is
//         L2/L3-resident, ~3us aggregate).
//     Conversion math unchanged => o bit-identical.
// K2 (solve_kernel): UNCHANGED from r6 (quad-split + phase-split, proven
//     scratch-free: VGPR 76, WRITE 1.8MB) -- surfaces in top-5 this round
//     for its first isolated measurement at this shape.

#define MM   20
#define PP   64
#define HH   256
#define EPSF 1e-12f

// quad-split storage: slot j (col 4j+h), rows 0..4j+3 at offset 2j(j+1);
// replicated col 20 at offset 60.
#define CSE(j, r) csx[2*(j)*((j)+1) + (r)]
#define C20(r)    csx[60 + (r)]

typedef __attribute__((ext_vector_type(8))) short bf16x8;
typedef __attribute__((ext_vector_type(4))) float f32x4;

static __device__ __forceinline__ unsigned short f2bf(float f) {
    unsigned int u = __builtin_bit_cast(unsigned int, f);
    u += 0x7fffu + ((u >> 16) & 1u);          // RNE
    return (unsigned short)(u >> 16);
}
static __device__ __forceinline__ float bf2f(unsigned short h) {
    unsigned int u = ((unsigned int)h) << 16;
    return __builtin_bit_cast(float, u);
}

__global__ __launch_bounds__(256, 2)
void mlp_mfma_kernel(const float* __restrict__ x,
                     const float* __restrict__ w1,
                     const float* __restrict__ b1,
                     const float* __restrict__ w2,
                     const float* __restrict__ b2,
                     float* __restrict__ o_out, int n)
{
    __shared__ __align__(16) short swh[PP * HH];   // 32 KB  w1 hi, frag order
    __shared__ __align__(16) short swl[PP * HH];   // 32 KB  w1 lo
    __shared__ float sb1[HH];                      // 1 KB
    __shared__ float sw2[HH];                      // 1 KB
    const int tid = threadIdx.x;

    // ---- stage w1 -> frag-ordered bf16 hi/lo, plus b1/w2 ----
    {
        const int col = tid;                       // 256 cols, one per thread
        const int t = col >> 4, nn = col & 15;
        #pragma unroll
        for (int g = 0; g < 8; ++g) {              // k = g*8 + u
            const int s = g >> 2, q = g & 3;
            bf16x8 hv, lv;
            #pragma unroll
            for (int u = 0; u < 8; ++u) {
                float v = w1[(g * 8 + u) * HH + col];
                unsigned short h = f2bf(v);
                hv[u] = (short)h;
                lv[u] = (short)f2bf(v - bf2f(h));
            }
            const int base = ((((t * 2 + s) * 4 + q) * 16) + nn) * 8;
            *(bf16x8*)&swh[base] = hv;
            *(bf16x8*)&swl[base] = lv;
        }
        sb1[tid] = b1[tid];
        sw2[tid] = w2[tid];
    }
    __syncthreads();

    const int lane = tid & 63;
    const int wv   = tid >> 6;
    const int nn   = lane & 15;      // A-row (node) / B-col (hidden) / C-col
    const int q    = lane >> 4;      // quad
    const int wb   = blockIdx.x * 128 + wv * 32;   // first node of this wave

    // ---- A fragments: 2 M-tiles x 2 k-steps, split hi/lo (32 VGPR) ----
    bf16x8 ah[2][2], al[2][2];
    #pragma unroll
    for (int mt = 0; mt < 2; ++mt) {
        const int row = wb + mt * 16 + nn;
        #pragma unroll
        for (int s = 0; s < 2; ++s) {
            float v[8];
            if (row < n) {
                const float* xp = x + (size_t)row * PP + s * 32 + q * 8;
                float4 va = *(const float4*)(xp);
                float4 vb = *(const float4*)(xp + 4);
                v[0]=va.x; v[1]=va.y; v[2]=va.z; v[3]=va.w;
                v[4]=vb.x; v[5]=vb.y; v[6]=vb.z; v[7]=vb.w;
            } else {
                #pragma unroll
                for (int u = 0; u < 8; ++u) v[u] = 0.0f;
            }
            bf16x8 h, l;
            #pragma unroll
            for (int u = 0; u < 8; ++u) {
                unsigned short hb = f2bf(v[u]);
                h[u] = (short)hb;
                l[u] = (short)f2bf(v[u] - bf2f(hb));
            }
            ah[mt][s] = h;
            al[mt][s] = l;
        }
    }

    float part[2][4];
    #pragma unroll
    for (int mt = 0; mt < 2; ++mt)
        #pragma unroll
        for (int r = 0; r < 4; ++r) part[mt][r] = 0.0f;

    // ---- hidden tiles: MFMA + fused bias/relu/dot; b1/w2 via LDS ----
    #pragma unroll
    for (int t = 0; t < 16; ++t) {
        f32x4 acc[2];
        #pragma unroll
        for (int mt = 0; mt < 2; ++mt) acc[mt] = (f32x4)(0.0f);
        #pragma unroll
        for (int s = 0; s < 2; ++s) {
            const int fb = ((((t * 2 + s) * 4 + q) * 16) + nn) * 8;
            bf16x8 bh = *(const bf16x8*)&swh[fb];
            bf16x8 bl = *(const bf16x8*)&swl[fb];
            #pragma unroll
            for (int mt = 0; mt < 2; ++mt) {
                acc[mt] = __builtin_amdgcn_mfma_f32_16x16x32_bf16(ah[mt][s], bh, acc[mt], 0, 0, 0);
                acc[mt] = __builtin_amdgcn_mfma_f32_16x16x32_bf16(al[mt][s], bh, acc[mt], 0, 0, 0);
                acc[mt] = __builtin_amdgcn_mfma_f32_16x16x32_bf16(ah[mt][s], bl, acc[mt], 0, 0, 0);
            }
        }
        const float b1t = sb1[t * 16 + nn];        // 4-lane broadcast reads
        const float w2t = sw2[t * 16 + nn];
        #pragma unroll
        for (int mt = 0; mt < 2; ++mt)
            #pragma unroll
            for (int r = 0; r < 4; ++r)
                part[mt][r] = fmaf(fmaxf(acc[mt][r] + b1t, 0.0f), w2t, part[mt][r]);
    }

    // ---- reduce over the 16 hidden-cols held by the quad's 16 lanes ----
    #pragma unroll
    for (int w = 1; w < 16; w <<= 1)
        #pragma unroll
        for (int mt = 0; mt < 2; ++mt)
            #pragma unroll
            for (int r = 0; r < 4; ++r)
                part[mt][r] += __shfl_xor(part[mt][r], w, 64);

    const float bb = b2[0];
    if (nn == 0) {
        #pragma unroll
        for (int mt = 0; mt < 2; ++mt) {
            const int row = wb + mt * 16 + q * 4;   // rows q*4+reg, reg=0..3
            if (row < n) {
                float4 o4 = make_float4(part[mt][0] + bb, part[mt][1] + bb,
                                        part[mt][2] + bb, part[mt][3] + bb);
                *(float4*)&o_out[row] = o4;
            }
        }
    }
}

// quad broadcast of sub-lane (s) within each 4-lane group, literal pattern
#define QSWZ(v, s) __builtin_bit_cast(float, __builtin_amdgcn_ds_swizzle( \
    __builtin_bit_cast(int, (v)), 0x8000 | (0x55 * (s))))

#define GATH(R) mall[R] = QSWZ(mv[(R) >> 2], (R) & 3);

// case K of phase P: copy pivot-row data (literal indices), broadcast pivot
#define SCASE(K, P) case K: {                                              \
    _Pragma("unroll")                                                      \
    for (int j = (P); j < 5; ++j) pk[j] = CSE(j, (K));                     \
    p20 = C20(K); pbv = bv[K];                                             \
    pd  = QSWZ(pk[(P)], (K) & 3);                                          \
} break;

__global__ __launch_bounds__(256, 2)
void solve_kernel(const float* __restrict__ pos,
                  const float* __restrict__ y,
                  const int*   __restrict__ nbr,
                  const float* __restrict__ theta,
                  const float* __restrict__ o_in,
                  float* __restrict__ yd,
                  float* __restrict__ od, int n)
{
    const int tid  = threadIdx.x;
    const int h_   = tid & 3;                         // column class
    const int i    = blockIdx.x * 64 + (tid >> 2);    // node (4 lanes/node)
    if (i >= n) return;

    const float sigma_sq = theta[0];
    const float phi      = theta[1];
    const float tau      = theta[2];
    const float tau_sq   = tau * sigma_sq;

    const float L2E = 1.44269504088896340736f;
    const float c1  = -phi * L2E;                       // exp(-phi*d) = exp2(c1*d)
    const float c0  = __builtin_amdgcn_logf(sigma_sq);  // log2(sigma^2)

    const float sqrtEPS = __builtin_amdgcn_sqrtf(EPSF);
    const float diagA   = __builtin_amdgcn_exp2f(fmaf(sqrtEPS, c1, c0)) + tau_sq;
    const float diagB   = sigma_sq + tau;               // border diagonal

    // ---- neighbor indices (static indices only) ----
    int idx[MM];
    const int4* nb4 = (const int4*)(nbr + (size_t)i * MM);
    #pragma unroll
    for (int k = 0; k < MM / 4; ++k) {
        int4 v = nb4[k];
        idx[4*k] = v.x; idx[4*k+1] = v.y; idx[4*k+2] = v.z; idx[4*k+3] = v.w;
    }

    // row coords (all 21, static-indexed)
    float px[21], py[21];
    const float2* pos2 = (const float2*)pos;
    #pragma unroll
    for (int j = 0; j < MM; ++j) {
        float2 p = pos2[idx[j]];
        px[j] = p.x; py[j] = p.y;
    }
    {
        float2 p = pos2[i];
        px[20] = p.x; py[20] = p.y;
    }

    // my columns' coords: re-gathered from nbr/pos (runtime ADDRESS is fine;
    // runtime index into a register array is not).
    float cx[5], cy[5];
    #pragma unroll
    for (int j = 0; j < 5; ++j) {
        int cj = nbr[(size_t)i * MM + 4*j + h_];
        float2 p = pos2[cj];
        cx[j] = p.x; cy[j] = p.y;
    }

    // border vector: lanes 0,2 carry y; lanes 1,3 carry o
    float bv[21];
    {
        const float* src = (h_ & 1) ? o_in : y;
        #pragma unroll
        for (int j = 0; j < MM; ++j) bv[j] = src[idx[j]];
        bv[20] = src[i];
    }

    // ---- build my slots (rows 0..4j+3 of col 4j+h) + replicated col 20 ----
    float csx[81];
    #pragma unroll
    for (int j = 0; j < 5; ++j) {
        #pragma unroll
        for (int r = 0; r <= 4*j + 3; ++r) {
            float dx = px[r] - cx[j];
            float dy = py[r] - cy[j];
            float d  = __builtin_amdgcn_sqrtf(fmaf(dx, dx, fmaf(dy, dy, EPSF)));
            float v  = __builtin_amdgcn_exp2f(fmaf(d, c1, c0));
            v = (r == 4*j + h_) ? diagA : v;       // diagonal of col 4j+h
            CSE(j, r) = v;
        }
    }
    #pragma unroll
    for (int r = 0; r < 20; ++r) {
        float dx = px[r] - px[20];
        float dy = py[r] - py[20];
        float d  = __builtin_amdgcn_sqrtf(fmaf(dx, dx, fmaf(dy, dy, EPSF)));
        C20(r)   = __builtin_amdgcn_exp2f(fmaf(d, c1, c0));
    }
    C20(20) = diagB;

    // ---- elimination: 5 phases x 4 rolled steps (round-0 shape per phase,
    //      round-1 range shrinking per phase). Omitted ops were exact no-ops.
    float pk[5], mv[5], mall[21], p20, pbv, pd;

    // ===== phase 0: k = 0..3, rows/slots/gathers from 0 =====
    #pragma unroll 1
    for (int k = 0; k < 4; ++k) {
        switch (k) {
        SCASE(0,0) SCASE(1,0) SCASE(2,0) SCASE(3,0)
        default: break;
        }
        float rp = __builtin_amdgcn_rcpf(pd);
        rp = rp * (2.0f - pd * rp);
        #pragma unroll
        for (int j = 0; j < 5; ++j)
            mv[j] = (4*j + h_ > k) ? pk[j] * rp : 0.0f;
        GATH(0)  GATH(1)  GATH(2)  GATH(3)  GATH(4)  GATH(5)  GATH(6)
        GATH(7)  GATH(8)  GATH(9)  GATH(10) GATH(11) GATH(12) GATH(13)
        GATH(14) GATH(15) GATH(16) GATH(17) GATH(18) GATH(19)
        mall[20] = p20 * rp;
        #pragma unroll
        for (int j = 0; j < 5; ++j) {
            float pkj = pk[j];
            #pragma unroll
            for (int r = 0; r <= 4*j + 3; ++r)
                CSE(j, r) = fmaf(-mall[r], pkj, CSE(j, r));
        }
        #pragma unroll
        for (int r = 0; r <= 20; ++r) {
            C20(r) = fmaf(-mall[r], p20, C20(r));
            bv[r]  = fmaf(-mall[r], pbv, bv[r]);
        }
    }

    // ===== phase 1: k = 4..7, rows >= 4, slots j >= 1 =====
    #pragma unroll 1
    for (int k = 4; k < 8; ++k) {
        switch (k) {
        SCASE(4,1) SCASE(5,1) SCASE(6,1) SCASE(7,1)
        default: break;
        }
        float rp = __builtin_amdgcn_rcpf(pd);
        rp = rp * (2.0f - pd * rp);
        #pragma unroll
        for (int j = 1; j < 5; ++j)
            mv[j] = (4*j + h_ > k) ? pk[j] * rp : 0.0f;
        GATH(4)  GATH(5)  GATH(6)  GATH(7)  GATH(8)  GATH(9)  GATH(10)
        GATH(11) GATH(12) GATH(13) GATH(14) GATH(15) GATH(16) GATH(17)
        GATH(18) GATH(19)
        mall[20] = p20 * rp;
        #pragma unroll
        for (int j = 1; j < 5; ++j) {
            float pkj = pk[j];
            #pragma unroll
            for (int r = 4; r <= 4*j + 3; ++r)
                CSE(j, r) = fmaf(-mall[r], pkj, CSE(j, r));
        }
        #pragma unroll
        for (int r = 4; r <= 20; ++r) {
            C20(r) = fmaf(-mall[r], p20, C20(r));
            bv[r]  = fmaf(-mall[r], pbv, bv[r]);
        }
    }

    // ===== phase 2: k = 8..11, rows >= 8, slots j >= 2 =====
    #pragma unroll 1
    for (int k = 8; k < 12; ++k) {
        switch (k) {
        SCASE(8,2) SCASE(9,2) SCASE(10,2) SCASE(11,2)
        default: break;
        }
        float rp = __builtin_amdgcn_rcpf(pd);
        rp = rp * (2.0f - pd * rp);
        #pragma unroll
        for (int j = 2; j < 5; ++j)
            mv[j] = (4*j + h_ > k) ? pk[j] * rp : 0.0f;
        GATH(8)  GATH(9)  GATH(10) GATH(11) GATH(12) GATH(13) GATH(14)
        GATH(15) GATH(16) GATH(17) GATH(18) GATH(19)
        mall[20] = p20 * rp;
        #pragma unroll
        for (int j = 2; j < 5; ++j) {
            float pkj = pk[j];
            #pragma unroll
            for (int r = 8; r <= 4*j + 3; ++r)
                CSE(j, r) = fmaf(-mall[r], pkj, CSE(j, r));
        }
        #pragma unroll
        for (int r = 8; r <= 20; ++r) {
            C20(r) = fmaf(-mall[r], p20, C20(r));
            bv[r]  = fmaf(-mall[r], pbv, bv[r]);
        }
    }

    // ===== phase 3: k = 12..15, rows >= 12, slots j >= 3 =====
    #pragma unroll 1
    for (int k = 12; k < 16; ++k) {
        switch (k) {
        SCASE(12,3) SCASE(13,3) SCASE(14,3) SCASE(15,3)
        default: break;
        }
        float rp = __builtin_amdgcn_rcpf(pd);
        rp = rp * (2.0f - pd * rp);
        #pragma unroll
        for (int j = 3; j < 5; ++j)
            mv[j] = (4*j + h_ > k) ? pk[j] * rp : 0.0f;
        GATH(12) GATH(13) GATH(14) GATH(15) GATH(16) GATH(17) GATH(18)
        GATH(19)
        mall[20] = p20 * rp;
        #pragma unroll
        for (int j = 3; j < 5; ++j) {
            float pkj = pk[j];
            #pragma unroll
            for (int r = 12; r <= 4*j + 3; ++r)
                CSE(j, r) = fmaf(-mall[r], pkj, CSE(j, r));
        }
        #pragma unroll
        for (int r = 12; r <= 20; ++r) {
            C20(r) = fmaf(-mall[r], p20, C20(r));
            bv[r]  = fmaf(-mall[r], pbv, bv[r]);
        }
    }

    // ===== phase 4: k = 16..19, rows >= 16, slot j = 4 =====
    #pragma unroll 1
    for (int k = 16; k < 20; ++k) {
        switch (k) {
        SCASE(16,4) SCASE(17,4) SCASE(18,4) SCASE(19,4)
        default: break;
        }
        float rp = __builtin_amdgcn_rcpf(pd);
        rp = rp * (2.0f - pd * rp);
        mv[4] = (16 + h_ > k) ? pk[4] * rp : 0.0f;
        GATH(16) GATH(17) GATH(18) GATH(19)
        mall[20] = p20 * rp;
        {
            float pkj = pk[4];
            #pragma unroll
            for (int r = 16; r <= 19; ++r)
                CSE(4, r) = fmaf(-mall[r], pkj, CSE(4, r));
        }
        #pragma unroll
        for (int r = 16; r <= 20; ++r) {
            C20(r) = fmaf(-mall[r], p20, C20(r));
            bv[r]  = fmaf(-mall[r], pbv, bv[r]);
        }
    }

    // f = a[20][20], replicated on every lane
    float f  = C20(20);
    float is = __builtin_amdgcn_rsqf(f);
    is = is * fmaf(-0.5f * f * is, is, 1.5f);

    if (h_ == 0)      yd[i] = bv[20] * is;   // lanes 0/2 carry y
    else if (h_ == 1) od[i] = bv[20] * is;   // lanes 1/3 carry o
}

extern "C" void kernel_launch(void* const* d_in, const int* in_sizes, int n_in,
                              void* d_out, int out_size, void* d_ws, size_t ws_size,
                              hipStream_t stream)
{
    const float* x     = (const float*)d_in[0];
    const float* pos   = (const float*)d_in[1];
    const float* y     = (const float*)d_in[2];
    const int*   nbr   = (const int*)  d_in[3];
    const float* theta = (const float*)d_in[4];
    const float* w1    = (const float*)d_in[5];
    const float* b1    = (const float*)d_in[6];
    const float* w2    = (const float*)d_in[7];
    const float* b2    = (const float*)d_in[8];

    const int n = in_sizes[2];                 // N
    float* out = (float*)d_out;
    float* yd = out;
    float* od = out + (size_t)n;
    float* oo = out + 2 * (size_t)n;

    // 128 nodes per 256-thread block (2 M-tiles per wave)
    mlp_mfma_kernel<<<(n + 127) / 128, 256, 0, stream>>>(x, w1, b1, w2, b2, oo, n);
    // 64 nodes per 256-thread block (4 lanes per node)
    solve_kernel<<<(n + 63) / 64, 256, 0, stream>>>(pos, y, nbr, theta, oo, yd, od, n);
}